// Round 10
// baseline (529.255 us; speedup 1.0000x reference)
//
#include <hip/hip_runtime.h>
#include <stdint.h>

#define B_   64
#define S_   197
#define D_   768
#define H_   12
#define F_   3072
#define BS_  (B_ * S_)   // 12608

typedef __attribute__((ext_vector_type(8))) short short8;
typedef __attribute__((ext_vector_type(4))) float f32x4;

__device__ __forceinline__ float bf2f(unsigned short h) {
    union { unsigned int u; float f; } v; v.u = ((unsigned int)h) << 16; return v.f;
}
__device__ __forceinline__ unsigned short f2bf(float f) {
    union { float f; unsigned int u; } v; v.f = f;
    unsigned int r = v.u + 0x7FFFu + ((v.u >> 16) & 1u);
    return (unsigned short)(r >> 16);
}

__device__ __forceinline__ void g2l16(const void* g, void* l) {
    __builtin_amdgcn_global_load_lds(
        (const __attribute__((address_space(1))) unsigned int*)g,
        (__attribute__((address_space(3))) unsigned int*)l, 16, 0, 0);
}

// exact-enough GELU: A&S 7.1.26 erf (max abs err 1.5e-7)
__device__ __forceinline__ float gelu_f(float c) {
    float z = fabsf(c) * 0.70710678118f;
    float t = __builtin_amdgcn_rcpf(1.f + 0.3275911f * z);
    float p = ((((1.061405429f * t - 1.453152027f) * t + 1.421413741f) * t
               - 0.284496736f) * t + 0.254829592f) * t;
    float erfv = 1.f - p * __expf(-z * z);
    erfv = c < 0.f ? -erfv : erfv;
    return 0.5f * c * (1.f + erfv);
}

// ---------------- fused weight transpose + bf16 cast + bias concat ----------------
__global__ __launch_bounds__(256)
void transpose_all(const float* __restrict__ Wq, const float* __restrict__ Wk,
                   const float* __restrict__ Wv, const float* __restrict__ Wo,
                   const float* __restrict__ W1, const float* __restrict__ W2,
                   const float* __restrict__ bq, const float* __restrict__ bk,
                   const float* __restrict__ bv,
                   unsigned short* __restrict__ wqkvT, unsigned short* __restrict__ woT,
                   unsigned short* __restrict__ w1T, unsigned short* __restrict__ w2T,
                   float* __restrict__ bcat) {
    int blk = blockIdx.x;
    int tx = threadIdx.x, ty = threadIdx.y;
    if (blk == 6912) {
        for (int i = ty * 32 + tx; i < 2304; i += 256)
            bcat[i] = i < 768 ? bq[i] : (i < 1536 ? bk[i - 768] : bv[i - 1536]);
        return;
    }
    const float* W; unsigned short* Wt; int K, N, rel, nx;
    if (blk < 2304) {
        int m = blk / 576; rel = blk - m * 576; K = 768; N = 768; nx = 24;
        W  = m == 0 ? Wq : m == 1 ? Wk : m == 2 ? Wv : Wo;
        Wt = m < 3 ? wqkvT + (size_t)m * 768 * 768 : woT;
    } else if (blk < 4608) {
        rel = blk - 2304; K = 768; N = 3072; nx = 96; W = W1; Wt = w1T;
    } else {
        rel = blk - 4608; K = 3072; N = 768; nx = 24; W = W2; Wt = w2T;
    }
    int n0 = (rel % nx) * 32, k0 = (rel / nx) * 32;
    __shared__ float t[32][33];
#pragma unroll
    for (int i = ty; i < 32; i += 8) t[i][tx] = W[(size_t)(k0 + i) * N + n0 + tx];
    __syncthreads();
#pragma unroll
    for (int i = ty; i < 32; i += 8) Wt[(size_t)(n0 + i) * K + k0 + tx] = f2bf(t[tx][i]);
}

// ---------------- LayerNorm: f32 in -> bf16 out ----------------
__global__ __launch_bounds__(256)
void ln_kernel(const float* __restrict__ x, const float* __restrict__ w,
               const float* __restrict__ b, unsigned short* __restrict__ out) {
    int row = blockIdx.x; size_t base = (size_t)row * 768;
    int tid = threadIdx.x;
    float v0 = x[base + tid], v1 = x[base + tid + 256], v2 = x[base + tid + 512];
    float s1 = v0 + v1 + v2;
    float s2 = v0 * v0 + v1 * v1 + v2 * v2;
#pragma unroll
    for (int off = 32; off > 0; off >>= 1) { s1 += __shfl_xor(s1, off); s2 += __shfl_xor(s2, off); }
    __shared__ float sa[4], sb[4];
    int w4 = tid >> 6;
    if ((tid & 63) == 0) { sa[w4] = s1; sb[w4] = s2; }
    __syncthreads();
    s1 = sa[0] + sa[1] + sa[2] + sa[3];
    s2 = sb[0] + sb[1] + sb[2] + sb[3];
    float mean = s1 * (1.f / 768.f);
    float var  = s2 * (1.f / 768.f) - mean * mean;
    float rstd = rsqrtf(var + 1e-6f);
    out[base + tid]       = f2bf((v0 - mean) * rstd * w[tid]       + b[tid]);
    out[base + tid + 256] = f2bf((v1 - mean) * rstd * w[tid + 256] + b[tid + 256]);
    out[base + tid + 512] = f2bf((v2 - mean) * rstd * w[tid + 512] + b[tid + 512]);
}

// ---------------- GEMM v7: 128x128 / BK=64, 4 waves, single-buffer, 3 blocks/CU --------
// C[M][N] = A[M][K](bf16) * Bt[N][K](bf16)^T + epilogue.
// The round's ONE lever: independent-block co-residency. LDS 32KB (single buffer),
// registers kept lean (acc 64 AGPR + ~80 arch) -> target 3 waves/SIMD = 3 independent
// 4-wave blocks/CU. Cross-block interleave hides staging/latency (m102: 1->2 blocks/CU
// was 320->833 TF; m114 co-schedule). Simple per-tile: {stage -> sync -> frag+MFMA -> sync}.
// No setprio (m190: hurts), no per-phase fences. Serpentine+m204 rank order kept (FETCH-
// optimal, R9-verified). Swizzle blk^=(row&7) both-sides (0 conflicts, R7/R8-verified).
// MODE 0: bf16 = acc+bias (cols<768 pre-scaled 0.125); MODE 1: f32 = acc+bias+resid;
// MODE 2: bf16 = gelu(acc+bias).
template<int MODE>
__global__ __launch_bounds__(256)
void gemmv7(const unsigned short* __restrict__ A, const unsigned short* __restrict__ Bt,
            const float* __restrict__ bias, const float* __restrict__ resid,
            void* __restrict__ out, int M, int N, int K, int NSUP) {
    constexpr int BK = 64;
    __shared__ unsigned short As[128 * BK];
    __shared__ unsigned short Bs[128 * BK];
    const int tid = threadIdx.x;
    const int l = tid & 63, w = tid >> 6;
    const int lr = l & 15, lg = l >> 4;
    const int wr = w >> 1, wc = w & 1;

    // ---- serpentine N-super rank order + m204 XCD chunking (R9-verified FETCH-optimal) ----
    const int nN = gridDim.x, nM = gridDim.y;
    const int nTot = nN * nM;
    const int orig = blockIdx.x + nN * blockIdx.y;
    const int q8 = nTot >> 3, r8 = nTot & 7;
    const int xcd = orig & 7, idx = orig >> 3;
    const int rank = (xcd < r8 ? xcd * (q8 + 1) : r8 * (q8 + 1) + (xcd - r8) * q8) + idx;
    const int fullg = nM * NSUP;
    const int sup = rank / fullg;
    const int rem = rank - sup * fullg;
    const int n0s = sup * NSUP;
    int wsup = nN - n0s; if (wsup > NSUP) wsup = NSUP;
    const int mloc = rem / wsup;
    const int nloc = rem - mloc * wsup;
    const int bm0 = mloc * 128;
    const int bn0 = (n0s + nloc) * 128;

    // staging: 4 calls per operand; call c = 32 rows x 128B; lane l -> row +(l>>3), blk l&7
    const int sr8 = l >> 3;                  // row within 8-row slab AND row&7 at dest
    const int slb = (l & 7) ^ sr8;           // pre-swizzled logical 16B block
    auto stage = [&](int kt) {
        const int k0 = kt * BK;
#pragma unroll
        for (int c = 0; c < 4; ++c) {
            int gr = bm0 + c * 32 + w * 8 + sr8; gr = gr < M ? gr : M - 1;
            g2l16(A + (size_t)gr * K + k0 + slb * 8, &As[(c * 32 + w * 8) * BK]);
            int gb = bn0 + c * 32 + w * 8 + sr8;
            g2l16(Bt + (size_t)gb * K + k0 + slb * 8, &Bs[(c * 32 + w * 8) * BK]);
        }
    };

    f32x4 acc[4][4];
#pragma unroll
    for (int i = 0; i < 4; ++i)
#pragma unroll
        for (int j = 0; j < 4; ++j) acc[i][j] = (f32x4){0.f, 0.f, 0.f, 0.f};

    const int NK = K / BK;                   // 12 or 48
    const int rsw = lr & 7;                  // read-side row XOR
    for (int kt = 0; kt < NK; ++kt) {
        stage(kt);
        __syncthreads();                     // staging landed (drains vmcnt)
        short8 bfr[4][2];
#pragma unroll
        for (int nt = 0; nt < 4; ++nt)
#pragma unroll
            for (int kk = 0; kk < 2; ++kk)
                bfr[nt][kk] = *(const short8*)&Bs[(wc * 64 + nt * 16 + lr) * BK +
                                                  (((kk * 4 + lg) ^ rsw) * 8)];
#pragma unroll
        for (int mt = 0; mt < 4; ++mt) {
            short8 af[2];
#pragma unroll
            for (int kk = 0; kk < 2; ++kk)
                af[kk] = *(const short8*)&As[(wr * 64 + mt * 16 + lr) * BK +
                                             (((kk * 4 + lg) ^ rsw) * 8)];
#pragma unroll
            for (int nt = 0; nt < 4; ++nt)
#pragma unroll
                for (int kk = 0; kk < 2; ++kk)
                    acc[mt][nt] = __builtin_amdgcn_mfma_f32_16x16x32_bf16(
                        af[kk], bfr[nt][kk], acc[mt][nt], 0, 0, 0);
        }
        __syncthreads();                     // all reads done before next overwrite
    }

#pragma unroll
    for (int mt = 0; mt < 4; ++mt)
#pragma unroll
        for (int nt = 0; nt < 4; ++nt)
#pragma unroll
            for (int r = 0; r < 4; ++r) {
                int gm = bm0 + wr * 64 + mt * 16 + lg * 4 + r;
                int gn = bn0 + wc * 64 + nt * 16 + lr;
                if (gm < M) {
                    float c = acc[mt][nt][r] + bias[gn];
                    if (MODE == 0) {
                        if (gn < 768) c *= 0.125f;   // fold 1/sqrt(Dh) into Q
                        ((unsigned short*)out)[(size_t)gm * N + gn] = f2bf(c);
                    } else if (MODE == 1) {
                        ((float*)out)[(size_t)gm * N + gn] = c + resid[(size_t)gm * N + gn];
                    } else {
                        ((unsigned short*)out)[(size_t)gm * N + gn] = f2bf(gelu_f(c));
                    }
                }
            }
}

// ---------------- MFMA attention: one block per (b,h), 4 waves ----------------
__global__ __launch_bounds__(256)
void attn_mfma(const unsigned short* __restrict__ qkv, const int* __restrict__ mask,
               unsigned short* __restrict__ ctx) {
    __shared__ unsigned short Ks[208 * 64];
    __shared__ unsigned short Vt[64 * 256];
    __shared__ unsigned short Psl[4][16 * 40];
    __shared__ float maskadj[224];
    const int bh = blockIdx.x, b = bh / 12, h = bh - b * 12;
    const int tid = threadIdx.x, l = tid & 63, w = tid >> 6;
    const int lr = l & 15, lg = l >> 4;
    const unsigned short* Qg = qkv + (size_t)b * 197 * 2304 + h * 64;
    const unsigned short* Kg = Qg + 768;
    const unsigned short* Vg = Qg + 1536;

    if (tid < 224)
        maskadj[tid] = tid < 197 ? -10000.f * (1.f - (float)mask[b * 197 + tid]) : -1e30f;

    for (int c = w; c < 26; c += 4) {
        int row = c * 8 + (l >> 3);
        int rc = row < 197 ? row : 196;
        int blk = (l & 7) ^ (row & 7);
        g2l16(Kg + (size_t)rc * 2304 + blk * 8, &Ks[c * 8 * 64]);
    }
    {
        int jj = tid >> 3, db = tid & 7;
#pragma unroll
        for (int it = 0; it < 7; ++it) {
            int j = it * 32 + jj;
            short8 v = (short8){0, 0, 0, 0, 0, 0, 0, 0};
            if (j < 197) v = *(const short8*)(Vg + (size_t)j * 2304 + db * 8);
#pragma unroll
            for (int e = 0; e < 8; ++e) {
                int d = db * 8 + e;
                Vt[d * 256 + (((j >> 3) ^ (d & 7)) * 8) + (j & 7)] = (unsigned short)v[e];
            }
        }
    }
    __syncthreads();

    for (int t = w; t < 13; t += 4) {
        const int q0 = t * 16;
        int qr = q0 + lr; qr = qr < 197 ? qr : 196;
        const short8 qf0 = *(const short8*)(Qg + (size_t)qr * 2304 + lg * 8);
        const short8 qf1 = *(const short8*)(Qg + (size_t)qr * 2304 + 32 + lg * 8);

        f32x4 sc[13];
#pragma unroll
        for (int kt = 0; kt < 13; ++kt) {
            const int krow = kt * 16 + lr;
            const short8 kf0 = *(const short8*)&Ks[krow * 64 + ((lg ^ (lr & 7)) * 8)];
            const short8 kf1 = *(const short8*)&Ks[krow * 64 + (((4 + lg) ^ (lr & 7)) * 8)];
            f32x4 a = (f32x4){0.f, 0.f, 0.f, 0.f};
            a = __builtin_amdgcn_mfma_f32_16x16x32_bf16(qf0, kf0, a, 0, 0, 0);
            a = __builtin_amdgcn_mfma_f32_16x16x32_bf16(qf1, kf1, a, 0, 0, 0);
            sc[kt] = a;
        }
        float mx[4] = {-1e30f, -1e30f, -1e30f, -1e30f};
#pragma unroll
        for (int kt = 0; kt < 13; ++kt) {
            float ma = maskadj[kt * 16 + lr];
#pragma unroll
            for (int r = 0; r < 4; ++r) {
                sc[kt][r] += ma;
                mx[r] = fmaxf(mx[r], sc[kt][r]);
            }
        }
#pragma unroll
        for (int r = 0; r < 4; ++r) {
            mx[r] = fmaxf(mx[r], __shfl_xor(mx[r], 1));
            mx[r] = fmaxf(mx[r], __shfl_xor(mx[r], 2));
            mx[r] = fmaxf(mx[r], __shfl_xor(mx[r], 4));
            mx[r] = fmaxf(mx[r], __shfl_xor(mx[r], 8));
        }
        float sm[4] = {0.f, 0.f, 0.f, 0.f};
#pragma unroll
        for (int kt = 0; kt < 13; ++kt)
#pragma unroll
            for (int r = 0; r < 4; ++r) {
                float p = __expf(sc[kt][r] - mx[r]);
                sc[kt][r] = p;
                sm[r] += p;
            }
#pragma unroll
        for (int r = 0; r < 4; ++r) {
            sm[r] += __shfl_xor(sm[r], 1);
            sm[r] += __shfl_xor(sm[r], 2);
            sm[r] += __shfl_xor(sm[r], 4);
            sm[r] += __shfl_xor(sm[r], 8);
            sm[r] = 1.f / sm[r];
        }
        f32x4 ao[4];
#pragma unroll
        for (int dt = 0; dt < 4; ++dt) ao[dt] = (f32x4){0.f, 0.f, 0.f, 0.f};
        unsigned short* Pw = &Psl[w][0];
#pragma unroll
        for (int ks = 0; ks < 7; ++ks) {
#pragma unroll
            for (int tl = 0; tl < 2; ++tl) {
                const int kt = ks * 2 + tl;
#pragma unroll
                for (int r = 0; r < 4; ++r) {
                    unsigned short pv = 0;
                    if (kt < 13) pv = f2bf(sc[kt][r] * sm[r]);
                    Pw[(lg * 4 + r) * 40 + tl * 16 + lr] = pv;
                }
            }
            const short8 pf = *(const short8*)&Pw[lr * 40 + lg * 8];
#pragma unroll
            for (int dt = 0; dt < 4; ++dt) {
                const int drow = dt * 16 + lr;
                const short8 vf = *(const short8*)&Vt[drow * 256 + (((4 * ks + lg) ^ (lr & 7)) * 8)];
                ao[dt] = __builtin_amdgcn_mfma_f32_16x16x32_bf16(vf, pf, ao[dt], 0, 0, 0);
            }
        }
        const int q = q0 + lr;
        if (q < 197) {
            unsigned short* crow = ctx + ((size_t)b * 197 + q) * 768 + h * 64;
#pragma unroll
            for (int dt = 0; dt < 4; ++dt) {
                union { unsigned short u[4]; uint2 v; } pk;
#pragma unroll
                for (int r = 0; r < 4; ++r) pk.u[r] = f2bf(ao[dt][r]);
                *(uint2*)(crow + dt * 16 + lg * 4) = pk.v;
            }
        }
    }
}

extern "C" void kernel_launch(void* const* d_in, const int* in_sizes, int n_in,
                              void* d_out, int out_size, void* d_ws, size_t ws_size,
                              hipStream_t stream) {
    const float* x    = (const float*)d_in[0];
    const float* Wq   = (const float*)d_in[1];
    const float* bq   = (const float*)d_in[2];
    const float* Wk   = (const float*)d_in[3];
    const float* bk   = (const float*)d_in[4];
    const float* Wv   = (const float*)d_in[5];
    const float* bv   = (const float*)d_in[6];
    const float* Wo   = (const float*)d_in[7];
    const float* bo   = (const float*)d_in[8];
    const float* ln1w = (const float*)d_in[9];
    const float* ln1b = (const float*)d_in[10];
    const float* W1   = (const float*)d_in[11];
    const float* b1   = (const float*)d_in[12];
    const float* W2   = (const float*)d_in[13];
    const float* b2   = (const float*)d_in[14];
    const float* ln2w = (const float*)d_in[15];
    const float* ln2b = (const float*)d_in[16];
    const int*   mask = (const int*)d_in[17];

    size_t off = 0;
    auto nxt = [&](size_t bytes) -> void* {
        void* r = (char*)d_ws + off; off += (bytes + 255) & ~(size_t)255; return r;
    };
    unsigned short* hbuf  = (unsigned short*)nxt((size_t)BS_ * 768 * 2);
    unsigned short* qkvg  = (unsigned short*)nxt((size_t)BS_ * 3072 * 2);  // QKV (2304), reused for FFN1 out (3072)
    unsigned short* wqkvT = (unsigned short*)nxt((size_t)2304 * 768 * 2);
    unsigned short* woT   = (unsigned short*)nxt((size_t)768 * 768 * 2);
    unsigned short* w1T   = (unsigned short*)nxt((size_t)3072 * 768 * 2);
    unsigned short* w2T   = (unsigned short*)nxt((size_t)768 * 3072 * 2);
    float*          bcat  = (float*)nxt(2304 * 4);
    unsigned short* ctx   = (unsigned short*)nxt((size_t)BS_ * 768 * 2);
    (void)ws_size; (void)in_sizes; (void)n_in; (void)out_size;

    transpose_all<<<6913, dim3(32, 8), 0, stream>>>(Wq, Wk, Wv, Wo, W1, W2, bq, bk, bv,
                                                    wqkvT, woT, w1T, w2T, bcat);
    ln_kernel<<<BS_, 256, 0, stream>>>(x, ln1w, ln1b, hbuf);
    // QKV: nN=18, NSUP=9 (B-super 1.77MB)
    gemmv7<0><<<dim3(18, 99), 256, 0, stream>>>(hbuf, wqkvT, bcat, nullptr, qkvg, BS_, 2304, 768, 9);
    attn_mfma<<<768, 256, 0, stream>>>(qkvg, mask, ctx);
    // O-proj: nN=6, NSUP=6 (whole B 1.2MB resident)
    gemmv7<1><<<dim3(6, 99), 256, 0, stream>>>(ctx, woT, bo, x, d_out, BS_, 768, 768, 6);
    ln_kernel<<<BS_, 256, 0, stream>>>((const float*)d_out, ln2w, ln2b, hbuf);
    // FFN1: nN=24, NSUP=12 (B-super 2.3MB)
    gemmv7<2><<<dim3(24, 99), 256, 0, stream>>>(hbuf, w1T, b1, nullptr, qkvg, BS_, 3072, 768, 12);
    // FFN2: K=3072, nN=6, NSUP=3 (B-super 2.36MB)
    gemmv7<1><<<dim3(6, 99), 256, 0, stream>>>(qkvg, w2T, b2, (const float*)d_out, d_out, BS_, 768, 3072, 3);
}

// Round 11
// 490.616 us; speedup vs baseline: 1.0788x; 1.0788x over previous
//
#include <hip/hip_runtime.h>
#include <stdint.h>

#define B_   64
#define S_   197
#define D_   768
#define H_   12
#define F_   3072
#define BS_  (B_ * S_)   // 12608

typedef __attribute__((ext_vector_type(8))) short short8;
typedef __attribute__((ext_vector_type(4))) float f32x4;

__device__ __forceinline__ float bf2f(unsigned short h) {
    union { unsigned int u; float f; } v; v.u = ((unsigned int)h) << 16; return v.f;
}
__device__ __forceinline__ unsigned short f2bf(float f) {
    union { float f; unsigned int u; } v; v.f = f;
    unsigned int r = v.u + 0x7FFFu + ((v.u >> 16) & 1u);
    return (unsigned short)(r >> 16);
}

__device__ __forceinline__ void g2l16(const void* g, void* l) {
    __builtin_amdgcn_global_load_lds(
        (const __attribute__((address_space(1))) unsigned int*)g,
        (__attribute__((address_space(3))) unsigned int*)l, 16, 0, 0);
}

// exact-enough GELU: A&S 7.1.26 erf (max abs err 1.5e-7)
__device__ __forceinline__ float gelu_f(float c) {
    float z = fabsf(c) * 0.70710678118f;
    float t = __builtin_amdgcn_rcpf(1.f + 0.3275911f * z);
    float p = ((((1.061405429f * t - 1.453152027f) * t + 1.421413741f) * t
               - 0.284496736f) * t + 0.254829592f) * t;
    float erfv = 1.f - p * __expf(-z * z);
    erfv = c < 0.f ? -erfv : erfv;
    return 0.5f * c * (1.f + erfv);
}

// ---------------- fused weight transpose + bf16 cast + bias concat ----------------
__global__ __launch_bounds__(256)
void transpose_all(const float* __restrict__ Wq, const float* __restrict__ Wk,
                   const float* __restrict__ Wv, const float* __restrict__ Wo,
                   const float* __restrict__ W1, const float* __restrict__ W2,
                   const float* __restrict__ bq, const float* __restrict__ bk,
                   const float* __restrict__ bv,
                   unsigned short* __restrict__ wqkvT, unsigned short* __restrict__ woT,
                   unsigned short* __restrict__ w1T, unsigned short* __restrict__ w2T,
                   float* __restrict__ bcat) {
    int blk = blockIdx.x;
    int tx = threadIdx.x, ty = threadIdx.y;
    if (blk == 6912) {
        for (int i = ty * 32 + tx; i < 2304; i += 256)
            bcat[i] = i < 768 ? bq[i] : (i < 1536 ? bk[i - 768] : bv[i - 1536]);
        return;
    }
    const float* W; unsigned short* Wt; int K, N, rel, nx;
    if (blk < 2304) {
        int m = blk / 576; rel = blk - m * 576; K = 768; N = 768; nx = 24;
        W  = m == 0 ? Wq : m == 1 ? Wk : m == 2 ? Wv : Wo;
        Wt = m < 3 ? wqkvT + (size_t)m * 768 * 768 : woT;
    } else if (blk < 4608) {
        rel = blk - 2304; K = 768; N = 3072; nx = 96; W = W1; Wt = w1T;
    } else {
        rel = blk - 4608; K = 3072; N = 768; nx = 24; W = W2; Wt = w2T;
    }
    int n0 = (rel % nx) * 32, k0 = (rel / nx) * 32;
    __shared__ float t[32][33];
#pragma unroll
    for (int i = ty; i < 32; i += 8) t[i][tx] = W[(size_t)(k0 + i) * N + n0 + tx];
    __syncthreads();
#pragma unroll
    for (int i = ty; i < 32; i += 8) Wt[(size_t)(n0 + i) * K + k0 + tx] = f2bf(t[tx][i]);
}

// ---------------- LayerNorm: f32 in -> bf16 out ----------------
__global__ __launch_bounds__(256)
void ln_kernel(const float* __restrict__ x, const float* __restrict__ w,
               const float* __restrict__ b, unsigned short* __restrict__ out) {
    int row = blockIdx.x; size_t base = (size_t)row * 768;
    int tid = threadIdx.x;
    float v0 = x[base + tid], v1 = x[base + tid + 256], v2 = x[base + tid + 512];
    float s1 = v0 + v1 + v2;
    float s2 = v0 * v0 + v1 * v1 + v2 * v2;
#pragma unroll
    for (int off = 32; off > 0; off >>= 1) { s1 += __shfl_xor(s1, off); s2 += __shfl_xor(s2, off); }
    __shared__ float sa[4], sb[4];
    int w4 = tid >> 6;
    if ((tid & 63) == 0) { sa[w4] = s1; sb[w4] = s2; }
    __syncthreads();
    s1 = sa[0] + sa[1] + sa[2] + sa[3];
    s2 = sb[0] + sb[1] + sb[2] + sb[3];
    float mean = s1 * (1.f / 768.f);
    float var  = s2 * (1.f / 768.f) - mean * mean;
    float rstd = rsqrtf(var + 1e-6f);
    out[base + tid]       = f2bf((v0 - mean) * rstd * w[tid]       + b[tid]);
    out[base + tid + 256] = f2bf((v1 - mean) * rstd * w[tid + 256] + b[tid + 256]);
    out[base + tid + 512] = f2bf((v2 - mean) * rstd * w[tid + 512] + b[tid + 512]);
}

// ---------------- GEMM v8: SINGLE-WAVE 64x64 / BK=32, barrier-free never-drain ring -----
// C[M][N] = A[M][K](bf16) * Bt[N][K](bf16)^T + epilogue. 64 threads = 1 wave per block.
// The round's ONE lever: guaranteed co-residency. LDS 16KB (2-buf) -> 10 independent
// blocks/CU; single-wave => NO barriers, per-wave counted vmcnt(8) never drains
// (m97@4096 proves 53 B/cyc/CU staging at 4 co-resident blocks vs 10 B/cyc at 1).
// Pipeline: prologue stages tiles 0,1; iter t: vmcnt(8) [tile t landed, t+1 in flight]
// -> ds_read frags -> restage tile t+2 into just-read buffer -> 16 MFMA.
// Swizzle (R3/R4-verified 0-conflict): read blk = lg ^ ((lr>>1)&3); write-side via
// pre-swizzled global source (l&3)^((l>>3)&3), linear LDS dest (rule 21).
// Serpentine N-super + m204 XCD rank order kept (R9-verified FETCH-optimal).
// M=12608=197*64 exactly, all N,K multiples of 64/32 -> no guards.
// MODE 0: bf16 = acc+bias (cols<768 pre-scaled 0.125); MODE 1: f32 = acc+bias+resid;
// MODE 2: bf16 = gelu(acc+bias).
template<int MODE>
__global__ __launch_bounds__(64, 3)
void gemm1w(const unsigned short* __restrict__ A, const unsigned short* __restrict__ Bt,
            const float* __restrict__ bias, const float* __restrict__ resid,
            void* __restrict__ out, int M, int N, int K, int NSUP) {
    constexpr int BK = 32;
    __shared__ unsigned short As[2][64 * BK];
    __shared__ unsigned short Bs[2][64 * BK];
    const int l = threadIdx.x;
    const int lr = l & 15, lg = l >> 4;

    // ---- serpentine N-super rank order + m204 XCD chunking ----
    const int nN = gridDim.x, nM = gridDim.y;
    const int nTot = nN * nM;
    const int orig = blockIdx.x + nN * blockIdx.y;
    const int q8 = nTot >> 3, r8 = nTot & 7;
    const int xcd = orig & 7, idx = orig >> 3;
    const int rank = (xcd < r8 ? xcd * (q8 + 1) : r8 * (q8 + 1) + (xcd - r8) * q8) + idx;
    const int fullg = nM * NSUP;
    const int sup = rank / fullg;
    const int rem = rank - sup * fullg;
    const int n0s = sup * NSUP;
    int wsup = nN - n0s; if (wsup > NSUP) wsup = NSUP;
    const int mloc = rem / wsup;
    const int nloc = rem - mloc * wsup;
    const int bm0 = mloc * 64;
    const int bn0 = (n0s + nloc) * 64;

    // staging: 4 g2l16 per operand per tile; call c = 16 rows x 64B.
    // lane l -> dest row c*16 + (l>>2), dest 16B-block l&3 (linear);
    // source provides logical block (l&3)^((l>>3)&3)  [write-side swizzle]
    const int srow = l >> 2;
    const int slb  = (l & 3) ^ ((l >> 3) & 3);
    const unsigned short* aBase = A  + (size_t)(bm0 + srow) * K + slb * 8;
    const unsigned short* bBase = Bt + (size_t)(bn0 + srow) * K + slb * 8;
    auto stage = [&](int buf, int kt) {
        const int k0 = kt * BK;
#pragma unroll
        for (int c = 0; c < 4; ++c) {
            g2l16(aBase + (size_t)c * 16 * K + k0, &As[buf][c * 16 * BK]);
            g2l16(bBase + (size_t)c * 16 * K + k0, &Bs[buf][c * 16 * BK]);
        }
    };

    f32x4 acc[4][4];
#pragma unroll
    for (int i = 0; i < 4; ++i)
#pragma unroll
        for (int j = 0; j < 4; ++j) acc[i][j] = (f32x4){0.f, 0.f, 0.f, 0.f};

    const int NK = K / BK;                    // 24 or 96
    stage(0, 0);
    stage(1, 1);

    const int rblk = (lg ^ ((lr >> 1) & 3)) * 8;   // read-side swizzled block offset (shorts)
    for (int kt = 0; kt < NK; ++kt) {
        const int buf = kt & 1;
        if (kt + 1 < NK) { asm volatile("s_waitcnt vmcnt(8)" ::: "memory"); }
        else             { asm volatile("s_waitcnt vmcnt(0)" ::: "memory"); }
        __builtin_amdgcn_sched_barrier(0);    // no LDS reads above the wait
        short8 af[4], bfr[4];
#pragma unroll
        for (int mt = 0; mt < 4; ++mt) af[mt]  = *(const short8*)&As[buf][(mt * 16 + lr) * BK + rblk];
#pragma unroll
        for (int nt = 0; nt < 4; ++nt) bfr[nt] = *(const short8*)&Bs[buf][(nt * 16 + lr) * BK + rblk];
        __builtin_amdgcn_sched_barrier(0);    // reads issued before restage overwrites
        if (kt + 2 < NK) stage(buf, kt + 2);  // refill just-read buffer (write lands >=200cyc later)
#pragma unroll
        for (int mt = 0; mt < 4; ++mt)
#pragma unroll
            for (int nt = 0; nt < 4; ++nt)
                acc[mt][nt] = __builtin_amdgcn_mfma_f32_16x16x32_bf16(af[mt], bfr[nt], acc[mt][nt], 0, 0, 0);
    }

#pragma unroll
    for (int mt = 0; mt < 4; ++mt)
#pragma unroll
        for (int nt = 0; nt < 4; ++nt)
#pragma unroll
            for (int r = 0; r < 4; ++r) {
                int gm = bm0 + mt * 16 + lg * 4 + r;
                int gn = bn0 + nt * 16 + lr;
                float c = acc[mt][nt][r] + bias[gn];
                if (MODE == 0) {
                    if (gn < 768) c *= 0.125f;   // fold 1/sqrt(Dh) into Q
                    ((unsigned short*)out)[(size_t)gm * N + gn] = f2bf(c);
                } else if (MODE == 1) {
                    ((float*)out)[(size_t)gm * N + gn] = c + resid[(size_t)gm * N + gn];
                } else {
                    ((unsigned short*)out)[(size_t)gm * N + gn] = f2bf(gelu_f(c));
                }
            }
}

// ---------------- MFMA attention: one block per (b,h), 4 waves ----------------
__global__ __launch_bounds__(256)
void attn_mfma(const unsigned short* __restrict__ qkv, const int* __restrict__ mask,
               unsigned short* __restrict__ ctx) {
    __shared__ unsigned short Ks[208 * 64];
    __shared__ unsigned short Vt[64 * 256];
    __shared__ unsigned short Psl[4][16 * 40];
    __shared__ float maskadj[224];
    const int bh = blockIdx.x, b = bh / 12, h = bh - b * 12;
    const int tid = threadIdx.x, l = tid & 63, w = tid >> 6;
    const int lr = l & 15, lg = l >> 4;
    const unsigned short* Qg = qkv + (size_t)b * 197 * 2304 + h * 64;
    const unsigned short* Kg = Qg + 768;
    const unsigned short* Vg = Qg + 1536;

    if (tid < 224)
        maskadj[tid] = tid < 197 ? -10000.f * (1.f - (float)mask[b * 197 + tid]) : -1e30f;

    for (int c = w; c < 26; c += 4) {
        int row = c * 8 + (l >> 3);
        int rc = row < 197 ? row : 196;
        int blk = (l & 7) ^ (row & 7);
        g2l16(Kg + (size_t)rc * 2304 + blk * 8, &Ks[c * 8 * 64]);
    }
    {
        int jj = tid >> 3, db = tid & 7;
#pragma unroll
        for (int it = 0; it < 7; ++it) {
            int j = it * 32 + jj;
            short8 v = (short8){0, 0, 0, 0, 0, 0, 0, 0};
            if (j < 197) v = *(const short8*)(Vg + (size_t)j * 2304 + db * 8);
#pragma unroll
            for (int e = 0; e < 8; ++e) {
                int d = db * 8 + e;
                Vt[d * 256 + (((j >> 3) ^ (d & 7)) * 8) + (j & 7)] = (unsigned short)v[e];
            }
        }
    }
    __syncthreads();

    for (int t = w; t < 13; t += 4) {
        const int q0 = t * 16;
        int qr = q0 + lr; qr = qr < 197 ? qr : 196;
        const short8 qf0 = *(const short8*)(Qg + (size_t)qr * 2304 + lg * 8);
        const short8 qf1 = *(const short8*)(Qg + (size_t)qr * 2304 + 32 + lg * 8);

        f32x4 sc[13];
#pragma unroll
        for (int kt = 0; kt < 13; ++kt) {
            const int krow = kt * 16 + lr;
            const short8 kf0 = *(const short8*)&Ks[krow * 64 + ((lg ^ (lr & 7)) * 8)];
            const short8 kf1 = *(const short8*)&Ks[krow * 64 + (((4 + lg) ^ (lr & 7)) * 8)];
            f32x4 a = (f32x4){0.f, 0.f, 0.f, 0.f};
            a = __builtin_amdgcn_mfma_f32_16x16x32_bf16(qf0, kf0, a, 0, 0, 0);
            a = __builtin_amdgcn_mfma_f32_16x16x32_bf16(qf1, kf1, a, 0, 0, 0);
            sc[kt] = a;
        }
        float mx[4] = {-1e30f, -1e30f, -1e30f, -1e30f};
#pragma unroll
        for (int kt = 0; kt < 13; ++kt) {
            float ma = maskadj[kt * 16 + lr];
#pragma unroll
            for (int r = 0; r < 4; ++r) {
                sc[kt][r] += ma;
                mx[r] = fmaxf(mx[r], sc[kt][r]);
            }
        }
#pragma unroll
        for (int r = 0; r < 4; ++r) {
            mx[r] = fmaxf(mx[r], __shfl_xor(mx[r], 1));
            mx[r] = fmaxf(mx[r], __shfl_xor(mx[r], 2));
            mx[r] = fmaxf(mx[r], __shfl_xor(mx[r], 4));
            mx[r] = fmaxf(mx[r], __shfl_xor(mx[r], 8));
        }
        float sm[4] = {0.f, 0.f, 0.f, 0.f};
#pragma unroll
        for (int kt = 0; kt < 13; ++kt)
#pragma unroll
            for (int r = 0; r < 4; ++r) {
                float p = __expf(sc[kt][r] - mx[r]);
                sc[kt][r] = p;
                sm[r] += p;
            }
#pragma unroll
        for (int r = 0; r < 4; ++r) {
            sm[r] += __shfl_xor(sm[r], 1);
            sm[r] += __shfl_xor(sm[r], 2);
            sm[r] += __shfl_xor(sm[r], 4);
            sm[r] += __shfl_xor(sm[r], 8);
            sm[r] = 1.f / sm[r];
        }
        f32x4 ao[4];
#pragma unroll
        for (int dt = 0; dt < 4; ++dt) ao[dt] = (f32x4){0.f, 0.f, 0.f, 0.f};
        unsigned short* Pw = &Psl[w][0];
#pragma unroll
        for (int ks = 0; ks < 7; ++ks) {
#pragma unroll
            for (int tl = 0; tl < 2; ++tl) {
                const int kt = ks * 2 + tl;
#pragma unroll
                for (int r = 0; r < 4; ++r) {
                    unsigned short pv = 0;
                    if (kt < 13) pv = f2bf(sc[kt][r] * sm[r]);
                    Pw[(lg * 4 + r) * 40 + tl * 16 + lr] = pv;
                }
            }
            const short8 pf = *(const short8*)&Pw[lr * 40 + lg * 8];
#pragma unroll
            for (int dt = 0; dt < 4; ++dt) {
                const int drow = dt * 16 + lr;
                const short8 vf = *(const short8*)&Vt[drow * 256 + (((4 * ks + lg) ^ (lr & 7)) * 8)];
                ao[dt] = __builtin_amdgcn_mfma_f32_16x16x32_bf16(vf, pf, ao[dt], 0, 0, 0);
            }
        }
        const int q = q0 + lr;
        if (q < 197) {
            unsigned short* crow = ctx + ((size_t)b * 197 + q) * 768 + h * 64;
#pragma unroll
            for (int dt = 0; dt < 4; ++dt) {
                union { unsigned short u[4]; uint2 v; } pk;
#pragma unroll
                for (int r = 0; r < 4; ++r) pk.u[r] = f2bf(ao[dt][r]);
                *(uint2*)(crow + dt * 16 + lg * 4) = pk.v;
            }
        }
    }
}

extern "C" void kernel_launch(void* const* d_in, const int* in_sizes, int n_in,
                              void* d_out, int out_size, void* d_ws, size_t ws_size,
                              hipStream_t stream) {
    const float* x    = (const float*)d_in[0];
    const float* Wq   = (const float*)d_in[1];
    const float* bq   = (const float*)d_in[2];
    const float* Wk   = (const float*)d_in[3];
    const float* bk   = (const float*)d_in[4];
    const float* Wv   = (const float*)d_in[5];
    const float* bv   = (const float*)d_in[6];
    const float* Wo   = (const float*)d_in[7];
    const float* bo   = (const float*)d_in[8];
    const float* ln1w = (const float*)d_in[9];
    const float* ln1b = (const float*)d_in[10];
    const float* W1   = (const float*)d_in[11];
    const float* b1   = (const float*)d_in[12];
    const float* W2   = (const float*)d_in[13];
    const float* b2   = (const float*)d_in[14];
    const float* ln2w = (const float*)d_in[15];
    const float* ln2b = (const float*)d_in[16];
    const int*   mask = (const int*)d_in[17];

    size_t off = 0;
    auto nxt = [&](size_t bytes) -> void* {
        void* r = (char*)d_ws + off; off += (bytes + 255) & ~(size_t)255; return r;
    };
    unsigned short* hbuf  = (unsigned short*)nxt((size_t)BS_ * 768 * 2);
    unsigned short* qkvg  = (unsigned short*)nxt((size_t)BS_ * 3072 * 2);  // QKV (2304), reused for FFN1 out (3072)
    unsigned short* wqkvT = (unsigned short*)nxt((size_t)2304 * 768 * 2);
    unsigned short* woT   = (unsigned short*)nxt((size_t)768 * 768 * 2);
    unsigned short* w1T   = (unsigned short*)nxt((size_t)3072 * 768 * 2);
    unsigned short* w2T   = (unsigned short*)nxt((size_t)768 * 3072 * 2);
    float*          bcat  = (float*)nxt(2304 * 4);
    unsigned short* ctx   = (unsigned short*)nxt((size_t)BS_ * 768 * 2);
    (void)ws_size; (void)in_sizes; (void)n_in; (void)out_size;

    transpose_all<<<6913, dim3(32, 8), 0, stream>>>(Wq, Wk, Wv, Wo, W1, W2, bq, bk, bv,
                                                    wqkvT, woT, w1T, w2T, bcat);
    ln_kernel<<<BS_, 256, 0, stream>>>(x, ln1w, ln1b, hbuf);
    // QKV: nN=36, NSUP=18 (B-super 1.73MB, 2 supers)
    gemm1w<0><<<dim3(36, 197), 64, 0, stream>>>(hbuf, wqkvT, bcat, nullptr, qkvg, BS_, 2304, 768, 18);
    attn_mfma<<<768, 256, 0, stream>>>(qkvg, mask, ctx);
    // O-proj: nN=12, NSUP=12 (whole B 1.15MB resident)
    gemm1w<1><<<dim3(12, 197), 64, 0, stream>>>(ctx, woT, bo, x, d_out, BS_, 768, 768, 12);
    ln_kernel<<<BS_, 256, 0, stream>>>((const float*)d_out, ln2w, ln2b, hbuf);
    // FFN1: nN=48, NSUP=24 (B-super 2.3MB, 2 supers)
    gemm1w<2><<<dim3(48, 197), 64, 0, stream>>>(hbuf, w1T, b1, nullptr, qkvg, BS_, 3072, 768, 24);
    // FFN2: K=3072, nN=12, NSUP=6 (B-super 2.3MB, 2 supers)
    gemm1w<1><<<dim3(12, 197), 64, 0, stream>>>(qkvg, w2T, b2, (const float*)d_out, d_out, BS_, 768, 3072, 6);
}

// Round 13
// 450.300 us; speedup vs baseline: 1.1753x; 1.0895x over previous
//
#include <hip/hip_runtime.h>
#include <stdint.h>

#define B_   64
#define S_   197
#define D_   768
#define H_   12
#define F_   3072
#define BS_  (B_ * S_)   // 12608

typedef __attribute__((ext_vector_type(8))) short short8;
typedef __attribute__((ext_vector_type(4))) float f32x4;

__device__ __forceinline__ float bf2f(unsigned short h) {
    union { unsigned int u; float f; } v; v.u = ((unsigned int)h) << 16; return v.f;
}
__device__ __forceinline__ unsigned short f2bf(float f) {
    union { float f; unsigned int u; } v; v.f = f;
    unsigned int r = v.u + 0x7FFFu + ((v.u >> 16) & 1u);
    return (unsigned short)(r >> 16);
}

__device__ __forceinline__ void g2l16(const void* g, void* l) {
    __builtin_amdgcn_global_load_lds(
        (const __attribute__((address_space(1))) unsigned int*)g,
        (__attribute__((address_space(3))) unsigned int*)l, 16, 0, 0);
}

// exact-enough GELU: A&S 7.1.26 erf (max abs err 1.5e-7)
__device__ __forceinline__ float gelu_f(float c) {
    float z = fabsf(c) * 0.70710678118f;
    float t = __builtin_amdgcn_rcpf(1.f + 0.3275911f * z);
    float p = ((((1.061405429f * t - 1.453152027f) * t + 1.421413741f) * t
               - 0.284496736f) * t + 0.254829592f) * t;
    float erfv = 1.f - p * __expf(-z * z);
    erfv = c < 0.f ? -erfv : erfv;
    return 0.5f * c * (1.f + erfv);
}

// ---------------- fused weight transpose + bf16 cast + bias concat ----------------
__global__ __launch_bounds__(256)
void transpose_all(const float* __restrict__ Wq, const float* __restrict__ Wk,
                   const float* __restrict__ Wv, const float* __restrict__ Wo,
                   const float* __restrict__ W1, const float* __restrict__ W2,
                   const float* __restrict__ bq, const float* __restrict__ bk,
                   const float* __restrict__ bv,
                   unsigned short* __restrict__ wqkvT, unsigned short* __restrict__ woT,
                   unsigned short* __restrict__ w1T, unsigned short* __restrict__ w2T,
                   float* __restrict__ bcat) {
    int blk = blockIdx.x;
    int tx = threadIdx.x, ty = threadIdx.y;
    if (blk == 6912) {
        for (int i = ty * 32 + tx; i < 2304; i += 256)
            bcat[i] = i < 768 ? bq[i] : (i < 1536 ? bk[i - 768] : bv[i - 1536]);
        return;
    }
    const float* W; unsigned short* Wt; int K, N, rel, nx;
    if (blk < 2304) {
        int m = blk / 576; rel = blk - m * 576; K = 768; N = 768; nx = 24;
        W  = m == 0 ? Wq : m == 1 ? Wk : m == 2 ? Wv : Wo;
        Wt = m < 3 ? wqkvT + (size_t)m * 768 * 768 : woT;
    } else if (blk < 4608) {
        rel = blk - 2304; K = 768; N = 3072; nx = 96; W = W1; Wt = w1T;
    } else {
        rel = blk - 4608; K = 3072; N = 768; nx = 24; W = W2; Wt = w2T;
    }
    int n0 = (rel % nx) * 32, k0 = (rel / nx) * 32;
    __shared__ float t[32][33];
#pragma unroll
    for (int i = ty; i < 32; i += 8) t[i][tx] = W[(size_t)(k0 + i) * N + n0 + tx];
    __syncthreads();
#pragma unroll
    for (int i = ty; i < 32; i += 8) Wt[(size_t)(n0 + i) * K + k0 + tx] = f2bf(t[tx][i]);
}

// ---------------- LayerNorm: f32 in -> bf16 out ----------------
__global__ __launch_bounds__(256)
void ln_kernel(const float* __restrict__ x, const float* __restrict__ w,
               const float* __restrict__ b, unsigned short* __restrict__ out) {
    int row = blockIdx.x; size_t base = (size_t)row * 768;
    int tid = threadIdx.x;
    float v0 = x[base + tid], v1 = x[base + tid + 256], v2 = x[base + tid + 512];
    float s1 = v0 + v1 + v2;
    float s2 = v0 * v0 + v1 * v1 + v2 * v2;
#pragma unroll
    for (int off = 32; off > 0; off >>= 1) { s1 += __shfl_xor(s1, off); s2 += __shfl_xor(s2, off); }
    __shared__ float sa[4], sb[4];
    int w4 = tid >> 6;
    if ((tid & 63) == 0) { sa[w4] = s1; sb[w4] = s2; }
    __syncthreads();
    s1 = sa[0] + sa[1] + sa[2] + sa[3];
    s2 = sb[0] + sb[1] + sb[2] + sb[3];
    float mean = s1 * (1.f / 768.f);
    float var  = s2 * (1.f / 768.f) - mean * mean;
    float rstd = rsqrtf(var + 1e-6f);
    out[base + tid]       = f2bf((v0 - mean) * rstd * w[tid]       + b[tid]);
    out[base + tid + 256] = f2bf((v1 - mean) * rstd * w[tid + 256] + b[tid + 256]);
    out[base + tid + 512] = f2bf((v2 - mean) * rstd * w[tid + 512] + b[tid + 512]);
}

// ---------------- GEMM v9b: phase template, ring-3, counted vmcnt, RACE-FIXED ----------
// Identical to R12 except the boundary is now {vmcnt(N) -> s_barrier -> reads}:
// the counted wait is per-wave, so every wave must pass its wait BEFORE any wave
// reads rows staged by other waves (R12 read immediately after its own wait -> NaN).
// GEOM 0: 512 thr / 8 waves (2Mx4N), 256x256 tile, wave 128x64, 2 phases/tile, LDS 96KB.
// GEOM 1: 256 thr / 4 waves (2Mx2N), 128x128 tile, wave 64x64, 1 phase/tile, LDS 48KB.
// Ring-3 LDS: tile t reads ring t%3, stages tile t+2 into (t+2)%3; boundary vmcnt(4)
// keeps tile t+1's 4 calls in flight (never drains until the last tile) — T4.
// Phase = {ds_read subtile -> issue stage calls -> s_barrier -> lgkmcnt(0)+
// sched_barrier(0) (rule 18) -> setprio(1) -> 16 MFMA -> setprio(0) -> s_barrier}.
// Swizzle + serpentine + m204 as verified in R3-R10.
template<int MODE, int GEOM>
__global__ __launch_bounds__(GEOM == 0 ? 512 : 256)
void gemm8ph(const unsigned short* __restrict__ A, const unsigned short* __restrict__ Bt,
             const float* __restrict__ bias, const float* __restrict__ resid,
             void* __restrict__ out, int M, int N, int K, int NSUP) {
    constexpr int BK  = 32;
    constexpr int BM  = GEOM == 0 ? 256 : 128;
    constexpr int BN  = GEOM == 0 ? 256 : 128;
    constexpr int NTH = GEOM == 0 ? 512 : 256;
    constexpr int WGN = GEOM == 0 ? 4 : 2;
    constexpr int WM  = GEOM == 0 ? 128 : 64;
    constexpr int WN  = 64;
    constexpr int MT  = WM / 16, NT = WN / 16;
    constexpr int PH  = MT / 4;                 // phases per K-tile (16 MFMA each)
    constexpr int RPC = NTH / 4;                // rows per stage call

    __shared__ unsigned short As[3][BM * BK];
    __shared__ unsigned short Bs[3][BN * BK];
    const int tid = threadIdx.x;
    const int l = tid & 63, wid = tid >> 6;
    const int lr = l & 15, lg = l >> 4;
    const int wr = wid / WGN, wc = wid % WGN;

    // ---- serpentine N-super rank order + m204 XCD chunking ----
    const int nN = gridDim.x, nM = gridDim.y;
    const int nTot = nN * nM;
    const int orig = blockIdx.x + nN * blockIdx.y;
    const int q8 = nTot >> 3, r8 = nTot & 7;
    const int xcd = orig & 7, idx = orig >> 3;
    const int rank = (xcd < r8 ? xcd * (q8 + 1) : r8 * (q8 + 1) + (xcd - r8) * q8) + idx;
    const int fullg = nM * NSUP;
    const int sup = rank / fullg;
    const int rem = rank - sup * fullg;
    const int n0s = sup * NSUP;
    int wsup = nN - n0s; if (wsup > NSUP) wsup = NSUP;
    const int mloc = rem / wsup;
    const int nloc = rem - mloc * wsup;
    const int bm0 = mloc * BM;
    const int bn0 = (n0s + nloc) * BN;

    // ---- staging (write-side swizzle via pre-swizzled source, linear dest) ----
    const int srow = wid * 16 + (l >> 2);       // row within one call's slab
    const int slb  = (l & 3) ^ ((l >> 3) & 3);  // pre-swizzled source 16B block
    auto stageHalf = [&](int ring, int kt, int half) {
        const int k0 = kt * BK;
        if (half == 0) {
#pragma unroll
            for (int c = 0; c < BM / RPC; ++c) {
                int gr = bm0 + c * RPC + srow; gr = gr < M ? gr : M - 1;
                g2l16(A + (size_t)gr * K + k0 + slb * 8, &As[ring][(c * RPC + wid * 16) * BK]);
            }
        } else {
#pragma unroll
            for (int c = 0; c < BN / RPC; ++c) {
                int gr = bn0 + c * RPC + srow;
                g2l16(Bt + (size_t)gr * K + k0 + slb * 8, &Bs[ring][(c * RPC + wid * 16) * BK]);
            }
        }
    };

    f32x4 acc[MT][NT];
#pragma unroll
    for (int i = 0; i < MT; ++i)
#pragma unroll
        for (int j = 0; j < NT; ++j) acc[i][j] = (f32x4){0.f, 0.f, 0.f, 0.f};

    const int NK = K / BK;
    // prologue: stage tiles 0 and 1 (8 calls in flight)
    stageHalf(0, 0, 0); stageHalf(0, 0, 1);
    stageHalf(1, 1, 0); stageHalf(1, 1, 1);

    const int rxor = (lr >> 1) & 3;             // read-side block XOR
    int ring = 0;
    for (int kt = 0; kt < NK; ++kt) {
        // boundary: tile kt landed for THIS wave; barrier makes it true for ALL waves
        if (kt + 1 < NK) { asm volatile("s_waitcnt vmcnt(4)" ::: "memory"); }
        else             { asm volatile("s_waitcnt vmcnt(0)" ::: "memory"); }
        __builtin_amdgcn_s_barrier();           // RACE FIX: all waves' tile-kt stages landed
        __builtin_amdgcn_sched_barrier(0);
        const unsigned short* Ab = &As[ring][0];
        const unsigned short* Bb = &Bs[ring][0];
        const int rnext = ring >= 1 ? ring - 1 : 2;     // (ring+2)%3
        const bool st = (kt + 2 < NK);

        short8 bfr[NT];
#pragma unroll
        for (int nt = 0; nt < NT; ++nt)
            bfr[nt] = *(const short8*)&Bb[(wc * WN + nt * 16 + lr) * BK + ((lg ^ rxor) * 8)];
#pragma unroll
        for (int ph = 0; ph < PH; ++ph) {
            short8 af[4];
#pragma unroll
            for (int mt = 0; mt < 4; ++mt)
                af[mt] = *(const short8*)&Ab[(wr * WM + (ph * 4 + mt) * 16 + lr) * BK + ((lg ^ rxor) * 8)];
            if (st) stageHalf(rnext, kt + 2, ph);       // PH==1 issues half 0 here
            if (PH == 1 && st) stageHalf(rnext, kt + 2, 1);
            __builtin_amdgcn_s_barrier();
            asm volatile("s_waitcnt lgkmcnt(0)" ::: "memory");
            __builtin_amdgcn_sched_barrier(0);
            __builtin_amdgcn_s_setprio(1);
#pragma unroll
            for (int mt = 0; mt < 4; ++mt)
#pragma unroll
                for (int nt = 0; nt < NT; ++nt)
                    acc[ph * 4 + mt][nt] = __builtin_amdgcn_mfma_f32_16x16x32_bf16(
                        af[mt], bfr[nt], acc[ph * 4 + mt][nt], 0, 0, 0);
            __builtin_amdgcn_s_setprio(0);
            __builtin_amdgcn_s_barrier();
        }
        ring = ring < 2 ? ring + 1 : 0;
    }

#pragma unroll
    for (int mt = 0; mt < MT; ++mt)
#pragma unroll
        for (int nt = 0; nt < NT; ++nt)
#pragma unroll
            for (int r = 0; r < 4; ++r) {
                int gm = bm0 + wr * WM + mt * 16 + lg * 4 + r;
                int gn = bn0 + wc * WN + nt * 16 + lr;
                if (gm < M) {
                    float c = acc[mt][nt][r] + bias[gn];
                    if (MODE == 0) {
                        if (gn < 768) c *= 0.125f;   // fold 1/sqrt(Dh) into Q
                        ((unsigned short*)out)[(size_t)gm * N + gn] = f2bf(c);
                    } else if (MODE == 1) {
                        ((float*)out)[(size_t)gm * N + gn] = c + resid[(size_t)gm * N + gn];
                    } else {
                        ((unsigned short*)out)[(size_t)gm * N + gn] = f2bf(gelu_f(c));
                    }
                }
            }
}

// ---------------- MFMA attention: one block per (b,h), 4 waves ----------------
__global__ __launch_bounds__(256)
void attn_mfma(const unsigned short* __restrict__ qkv, const int* __restrict__ mask,
               unsigned short* __restrict__ ctx) {
    __shared__ unsigned short Ks[208 * 64];
    __shared__ unsigned short Vt[64 * 256];
    __shared__ unsigned short Psl[4][16 * 40];
    __shared__ float maskadj[224];
    const int bh = blockIdx.x, b = bh / 12, h = bh - b * 12;
    const int tid = threadIdx.x, l = tid & 63, w = tid >> 6;
    const int lr = l & 15, lg = l >> 4;
    const unsigned short* Qg = qkv + (size_t)b * 197 * 2304 + h * 64;
    const unsigned short* Kg = Qg + 768;
    const unsigned short* Vg = Qg + 1536;

    if (tid < 224)
        maskadj[tid] = tid < 197 ? -10000.f * (1.f - (float)mask[b * 197 + tid]) : -1e30f;

    for (int c = w; c < 26; c += 4) {
        int row = c * 8 + (l >> 3);
        int rc = row < 197 ? row : 196;
        int blk = (l & 7) ^ (row & 7);
        g2l16(Kg + (size_t)rc * 2304 + blk * 8, &Ks[c * 8 * 64]);
    }
    {
        int jj = tid >> 3, db = tid & 7;
#pragma unroll
        for (int it = 0; it < 7; ++it) {
            int j = it * 32 + jj;
            short8 v = (short8){0, 0, 0, 0, 0, 0, 0, 0};
            if (j < 197) v = *(const short8*)(Vg + (size_t)j * 2304 + db * 8);
#pragma unroll
            for (int e = 0; e < 8; ++e) {
                int d = db * 8 + e;
                Vt[d * 256 + (((j >> 3) ^ (d & 7)) * 8) + (j & 7)] = (unsigned short)v[e];
            }
        }
    }
    __syncthreads();

    for (int t = w; t < 13; t += 4) {
        const int q0 = t * 16;
        int qr = q0 + lr; qr = qr < 197 ? qr : 196;
        const short8 qf0 = *(const short8*)(Qg + (size_t)qr * 2304 + lg * 8);
        const short8 qf1 = *(const short8*)(Qg + (size_t)qr * 2304 + 32 + lg * 8);

        f32x4 sc[13];
#pragma unroll
        for (int kt = 0; kt < 13; ++kt) {
            const int krow = kt * 16 + lr;
            const short8 kf0 = *(const short8*)&Ks[krow * 64 + ((lg ^ (lr & 7)) * 8)];
            const short8 kf1 = *(const short8*)&Ks[krow * 64 + (((4 + lg) ^ (lr & 7)) * 8)];
            f32x4 a = (f32x4){0.f, 0.f, 0.f, 0.f};
            a = __builtin_amdgcn_mfma_f32_16x16x32_bf16(qf0, kf0, a, 0, 0, 0);
            a = __builtin_amdgcn_mfma_f32_16x16x32_bf16(qf1, kf1, a, 0, 0, 0);
            sc[kt] = a;
        }
        float mx[4] = {-1e30f, -1e30f, -1e30f, -1e30f};
#pragma unroll
        for (int kt = 0; kt < 13; ++kt) {
            float ma = maskadj[kt * 16 + lr];
#pragma unroll
            for (int r = 0; r < 4; ++r) {
                sc[kt][r] += ma;
                mx[r] = fmaxf(mx[r], sc[kt][r]);
            }
        }
#pragma unroll
        for (int r = 0; r < 4; ++r) {
            mx[r] = fmaxf(mx[r], __shfl_xor(mx[r], 1));
            mx[r] = fmaxf(mx[r], __shfl_xor(mx[r], 2));
            mx[r] = fmaxf(mx[r], __shfl_xor(mx[r], 4));
            mx[r] = fmaxf(mx[r], __shfl_xor(mx[r], 8));
        }
        float sm[4] = {0.f, 0.f, 0.f, 0.f};
#pragma unroll
        for (int kt = 0; kt < 13; ++kt)
#pragma unroll
            for (int r = 0; r < 4; ++r) {
                float p = __expf(sc[kt][r] - mx[r]);
                sc[kt][r] = p;
                sm[r] += p;
            }
#pragma unroll
        for (int r = 0; r < 4; ++r) {
            sm[r] += __shfl_xor(sm[r], 1);
            sm[r] += __shfl_xor(sm[r], 2);
            sm[r] += __shfl_xor(sm[r], 4);
            sm[r] += __shfl_xor(sm[r], 8);
            sm[r] = 1.f / sm[r];
        }
        f32x4 ao[4];
#pragma unroll
        for (int dt = 0; dt < 4; ++dt) ao[dt] = (f32x4){0.f, 0.f, 0.f, 0.f};
        unsigned short* Pw = &Psl[w][0];
#pragma unroll
        for (int ks = 0; ks < 7; ++ks) {
#pragma unroll
            for (int tl = 0; tl < 2; ++tl) {
                const int kt = ks * 2 + tl;
#pragma unroll
                for (int r = 0; r < 4; ++r) {
                    unsigned short pv = 0;
                    if (kt < 13) pv = f2bf(sc[kt][r] * sm[r]);
                    Pw[(lg * 4 + r) * 40 + tl * 16 + lr] = pv;
                }
            }
            const short8 pf = *(const short8*)&Pw[lr * 40 + lg * 8];
#pragma unroll
            for (int dt = 0; dt < 4; ++dt) {
                const int drow = dt * 16 + lr;
                const short8 vf = *(const short8*)&Vt[drow * 256 + (((4 * ks + lg) ^ (lr & 7)) * 8)];
                ao[dt] = __builtin_amdgcn_mfma_f32_16x16x32_bf16(vf, pf, ao[dt], 0, 0, 0);
            }
        }
        const int q = q0 + lr;
        if (q < 197) {
            unsigned short* crow = ctx + ((size_t)b * 197 + q) * 768 + h * 64;
#pragma unroll
            for (int dt = 0; dt < 4; ++dt) {
                union { unsigned short u[4]; uint2 v; } pk;
#pragma unroll
                for (int r = 0; r < 4; ++r) pk.u[r] = f2bf(ao[dt][r]);
                *(uint2*)(crow + dt * 16 + lg * 4) = pk.v;
            }
        }
    }
}

extern "C" void kernel_launch(void* const* d_in, const int* in_sizes, int n_in,
                              void* d_out, int out_size, void* d_ws, size_t ws_size,
                              hipStream_t stream) {
    const float* x    = (const float*)d_in[0];
    const float* Wq   = (const float*)d_in[1];
    const float* bq   = (const float*)d_in[2];
    const float* Wk   = (const float*)d_in[3];
    const float* bk   = (const float*)d_in[4];
    const float* Wv   = (const float*)d_in[5];
    const float* bv   = (const float*)d_in[6];
    const float* Wo   = (const float*)d_in[7];
    const float* bo   = (const float*)d_in[8];
    const float* ln1w = (const float*)d_in[9];
    const float* ln1b = (const float*)d_in[10];
    const float* W1   = (const float*)d_in[11];
    const float* b1   = (const float*)d_in[12];
    const float* W2   = (const float*)d_in[13];
    const float* b2   = (const float*)d_in[14];
    const float* ln2w = (const float*)d_in[15];
    const float* ln2b = (const float*)d_in[16];
    const int*   mask = (const int*)d_in[17];

    size_t off = 0;
    auto nxt = [&](size_t bytes) -> void* {
        void* r = (char*)d_ws + off; off += (bytes + 255) & ~(size_t)255; return r;
    };
    unsigned short* hbuf  = (unsigned short*)nxt((size_t)BS_ * 768 * 2);
    unsigned short* qkvg  = (unsigned short*)nxt((size_t)BS_ * 3072 * 2);  // QKV (2304), reused for FFN1 out (3072)
    unsigned short* wqkvT = (unsigned short*)nxt((size_t)2304 * 768 * 2);
    unsigned short* woT   = (unsigned short*)nxt((size_t)768 * 768 * 2);
    unsigned short* w1T   = (unsigned short*)nxt((size_t)3072 * 768 * 2);
    unsigned short* w2T   = (unsigned short*)nxt((size_t)768 * 3072 * 2);
    float*          bcat  = (float*)nxt(2304 * 4);
    unsigned short* ctx   = (unsigned short*)nxt((size_t)BS_ * 768 * 2);
    (void)ws_size; (void)in_sizes; (void)n_in; (void)out_size;

    transpose_all<<<6913, dim3(32, 8), 0, stream>>>(Wq, Wk, Wv, Wo, W1, W2, bq, bk, bv,
                                                    wqkvT, woT, w1T, w2T, bcat);
    ln_kernel<<<BS_, 256, 0, stream>>>(x, ln1w, ln1b, hbuf);
    // QKV: GEOM0, nN=9, NSUP=5 (B-super 2.0MB)
    gemm8ph<0, 0><<<dim3(9, 50), 512, 0, stream>>>(hbuf, wqkvT, bcat, nullptr, qkvg, BS_, 2304, 768, 5);
    attn_mfma<<<768, 256, 0, stream>>>(qkvg, mask, ctx);
    // O-proj: GEOM1, nN=6, NSUP=6 (whole B 1.2MB resident)
    gemm8ph<1, 1><<<dim3(6, 99), 256, 0, stream>>>(ctx, woT, bo, x, d_out, BS_, 768, 768, 6);
    ln_kernel<<<BS_, 256, 0, stream>>>((const float*)d_out, ln2w, ln2b, hbuf);
    // FFN1: GEOM0, nN=12, NSUP=6 (B-super 2.4MB)
    gemm8ph<2, 0><<<dim3(12, 50), 512, 0, stream>>>(hbuf, w1T, b1, nullptr, qkvg, BS_, 3072, 768, 6);
    // FFN2: GEOM1, K=3072, nN=6, NSUP=3 (B-super 2.4MB)
    gemm8ph<1, 1><<<dim3(6, 99), 256, 0, stream>>>(qkvg, w2T, b2, (const float*)d_out, d_out, BS_, 768, 3072, 3);
}